// Round 1
// baseline (478.763 us; speedup 1.0000x reference)
//
#include <hip/hip_runtime.h>
#include <hip/hip_bf16.h>

#define NTOK 16384
#define HD   4096
#define NE   64
#define TTILE 32            // tokens per block
#define NBLK (NTOK / TTILE) // 512 blocks -> 2 blocks/CU
#define NIT  (HD / 32)      // 128 k-tiles

// LDS: logits tile stride (floats)
#define SL  68

// ws layout (floats): [0,64)=P_sum, [64,128)=counts, [128]=z_sum, pad to 192,
// then Bhi (bf16, NE*HD elems), then Blo (bf16, NE*HD elems). Total ~1.05 MB.
#define WS_ACC_FLOATS 192
#define B_ELEMS (NE * HD)

typedef __bf16 bf16x8 __attribute__((ext_vector_type(8)));
typedef __bf16 bf16x4 __attribute__((ext_vector_type(4)));
typedef float  f32x4  __attribute__((ext_vector_type(4)));

__device__ __forceinline__ f32x4 mfma16(bf16x8 a, bf16x8 b, f32x4 c) {
    return __builtin_amdgcn_mfma_f32_16x16x32_bf16(a, b, c, 0, 0, 0);
}

__device__ __forceinline__ void cvt_split(float4 v, bf16x4& hi, bf16x4& lo) {
    float x[4] = {v.x, v.y, v.z, v.w};
    #pragma unroll
    for (int e = 0; e < 4; ++e) {
        __bf16 h = (__bf16)x[e];        // RNE
        hi[e] = h;
        lo[e] = (__bf16)(x[e] - (float)h);
    }
}

__global__ void zero_ws_kernel(float* ws) {
    int i = threadIdx.x;
    if (i < 129) ws[i] = 0.0f;
}

// One-shot: zero accumulators + convert W_gate fp32 -> bf16 hi/lo in ws.
// Grid 128 x 256 threads, 8 elems/thread = 64*4096 elems exactly.
__global__ __launch_bounds__(256) void prep_kernel(
    const float* __restrict__ Wg, float* __restrict__ ws)
{
    const int tid = threadIdx.x;
    if (blockIdx.x == 0 && tid < 129) ws[tid] = 0.0f;
    __bf16* Bhi = (__bf16*)(ws + WS_ACC_FLOATS);
    __bf16* Blo = Bhi + B_ELEMS;
    const int i = (blockIdx.x * 256 + tid) * 8;
    float4 v0 = *(const float4*)(Wg + i);
    float4 v1 = *(const float4*)(Wg + i + 4);
    bf16x4 h0, l0, h1, l1;
    cvt_split(v0, h0, l0);
    cvt_split(v1, h1, l1);
    *(bf16x4*)(Bhi + i)     = h0;
    *(bf16x4*)(Bhi + i + 4) = h1;
    *(bf16x4*)(Blo + i)     = l0;
    *(bf16x4*)(Blo + i + 4) = l1;
}

// Main router: barrier-free register-resident GEMM main loop, no LDS staging.
// Each wave: 16 tokens x 32 experts. wv0/wv1 share tokens (L1 hit on A),
// wv0/wv2 share experts (L1 hit on B).
template<bool PRE>
__global__ __launch_bounds__(256) void router_kernel(
    const float* __restrict__ hs,
    const float* __restrict__ Wg,
    const __bf16* __restrict__ Bhi,
    const __bf16* __restrict__ Blo,
    float* __restrict__ out,
    float* __restrict__ ws)
{
    __shared__ float sLog[TTILE * SL];   // 8,704 B
    __shared__ float sInv[TTILE];
    __shared__ float sPp[4 * 64];
    __shared__ float sCnt[64];
    __shared__ float sZ;

    const int tid = threadIdx.x;
    const int t0  = blockIdx.x * TTILE;

    if (tid < 64) sCnt[tid] = 0.0f;
    if (tid == 0) sZ = 0.0f;

    const int lane = tid & 63;
    const int wv   = tid >> 6;
    const int wr   = (wv >> 1) * 16;    // token offset: 0 or 16
    const int wc   = (wv & 1) * 32;     // expert offset: 0 or 32
    const int fm   = lane & 15;
    const int fq   = lane >> 4;         // 0..3
    const int fk   = fq * 8;            // k offset within 32-tile

    // A: each lane owns 8 contiguous k-floats of one token row -> direct load
    const float* pA = hs + (size_t)(t0 + wr + fm) * HD + fk;

    // B fragment pointers (expert row = wc + j*16 + fm, same fk)
    const __bf16* pBh = nullptr;
    const __bf16* pBl = nullptr;
    const float*  pBf = nullptr;
    if constexpr (PRE) {
        pBh = Bhi + (size_t)(wc + fm) * HD + fk;
        pBl = Blo + (size_t)(wc + fm) * HD + fk;
    } else {
        pBf = Wg + (size_t)(wc + fm) * HD + fk;
    }

    f32x4 acc[2];
    acc[0] = (f32x4){0.f, 0.f, 0.f, 0.f};
    acc[1] = (f32x4){0.f, 0.f, 0.f, 0.f};

    auto step = [&](float4 ca0, float4 ca1) {
        bf16x8 bh0, bl0, bh1, bl1;
        if constexpr (PRE) {
            bh0 = *(const bf16x8*)(pBh);
            bh1 = *(const bf16x8*)(pBh + 16 * HD);
            bl0 = *(const bf16x8*)(pBl);
            bl1 = *(const bf16x8*)(pBl + 16 * HD);
            pBh += 32; pBl += 32;
        } else {
            float4 f00 = *(const float4*)(pBf);
            float4 f01 = *(const float4*)(pBf + 4);
            float4 f10 = *(const float4*)(pBf + 16 * HD);
            float4 f11 = *(const float4*)(pBf + 16 * HD + 4);
            pBf += 32;
            bf16x4 h, l;
            cvt_split(f00, h, l);
            #pragma unroll
            for (int e = 0; e < 4; ++e) { bh0[e] = h[e]; bl0[e] = l[e]; }
            cvt_split(f01, h, l);
            #pragma unroll
            for (int e = 0; e < 4; ++e) { bh0[4+e] = h[e]; bl0[4+e] = l[e]; }
            cvt_split(f10, h, l);
            #pragma unroll
            for (int e = 0; e < 4; ++e) { bh1[e] = h[e]; bl1[e] = l[e]; }
            cvt_split(f11, h, l);
            #pragma unroll
            for (int e = 0; e < 4; ++e) { bh1[4+e] = h[e]; bl1[4+e] = l[e]; }
        }
        bf16x8 ahi, alo;
        {
            bf16x4 h, l;
            cvt_split(ca0, h, l);
            #pragma unroll
            for (int e = 0; e < 4; ++e) { ahi[e] = h[e]; alo[e] = l[e]; }
            cvt_split(ca1, h, l);
            #pragma unroll
            for (int e = 0; e < 4; ++e) { ahi[4+e] = h[e]; alo[4+e] = l[e]; }
        }
        // 4-term exact split, same accumulation order as the passing kernel
        acc[0] = mfma16(ahi, bh0, acc[0]);
        acc[0] = mfma16(ahi, bl0, acc[0]);
        acc[0] = mfma16(alo, bh0, acc[0]);
        acc[0] = mfma16(alo, bl0, acc[0]);
        acc[1] = mfma16(ahi, bh1, acc[1]);
        acc[1] = mfma16(ahi, bl1, acc[1]);
        acc[1] = mfma16(alo, bh1, acc[1]);
        acc[1] = mfma16(alo, bl1, acc[1]);
    };

    // Barrier-free main loop with 1-deep A prefetch (HBM latency hiding);
    // B is L1/L2-resident, loaded in-iteration.
    float4 a0 = *(const float4*)(pA);
    float4 a1 = *(const float4*)(pA + 4);
    for (int it = 0; it < NIT - 1; ++it) {
        float4 n0 = *(const float4*)(pA + 32);
        float4 n1 = *(const float4*)(pA + 36);
        pA += 32;
        step(a0, a1);
        a0 = n0; a1 = n1;
    }
    step(a0, a1);

    // ---- scatter logits to LDS: C/D layout col=lane&15 (expert), row=fq*4+reg
    #pragma unroll
    for (int j = 0; j < 2; ++j)
        #pragma unroll
        for (int r = 0; r < 4; ++r) {
            const int tokl = wr + fq * 4 + r;
            const int expl = wc + j * 16 + fm;
            sLog[tokl * SL + expl] = acc[j][r];
        }
    __syncthreads();

    // ---- phase 2a: softmax/top-2; 8 lanes per token, 8 experts per lane
    const int g = tid >> 3;       // token 0..31
    const int l = tid & 7;
    float* Lrow = &sLog[g * SL + l * 8];
    float lv[8];
    float m = -3.0e38f;
    #pragma unroll
    for (int c = 0; c < 8; ++c) { lv[c] = Lrow[c]; m = fmaxf(m, lv[c]); }
    m = fmaxf(m, __shfl_xor(m, 1, 64));
    m = fmaxf(m, __shfl_xor(m, 2, 64));
    m = fmaxf(m, __shfl_xor(m, 4, 64));

    float v1 = -3.0e38f, v2 = -3.0e38f; int i1 = 0, i2 = 0;
    float ssum = 0.0f;
    #pragma unroll
    for (int c = 0; c < 8; ++c) {
        const float val = lv[c]; const int idx = l * 8 + c;
        const float ev = __expf(val - m);
        Lrow[c] = ev;               // overwrite logits with exp(l - m)
        ssum += ev;
        if (val > v1) { v2 = v1; i2 = i1; v1 = val; i1 = idx; }
        else if (val > v2) { v2 = val; i2 = idx; }
    }
    ssum += __shfl_xor(ssum, 1, 64);
    ssum += __shfl_xor(ssum, 2, 64);
    ssum += __shfl_xor(ssum, 4, 64);

    #pragma unroll
    for (int s = 1; s <= 4; s <<= 1) {
        const float ov1 = __shfl_xor(v1, s, 64);
        const int   oi1 = __shfl_xor(i1, s, 64);
        const float ov2 = __shfl_xor(v2, s, 64);
        const int   oi2 = __shfl_xor(i2, s, 64);
        float n1, n2; int ni1, ni2;
        const bool ofirst = (ov1 > v1) || (ov1 == v1 && oi1 < i1);
        if (ofirst) {
            n1 = ov1; ni1 = oi1;
            const bool osec = (ov2 > v1) || (ov2 == v1 && oi2 < i1);
            n2 = osec ? ov2 : v1; ni2 = osec ? oi2 : i1;
        } else {
            n1 = v1; ni1 = i1;
            const bool asec = (v2 > ov1) || (v2 == ov1 && i2 < oi1);
            n2 = asec ? v2 : ov1; ni2 = asec ? i2 : oi1;
        }
        v1 = n1; i1 = ni1; v2 = n2; i2 = ni2;
    }

    if (l == 0) {
        const float e1 = __expf(v1 - m), e2 = __expf(v2 - m);
        const float winv = 1.0f / (e1 + e2);
        const int token = t0 + g;
        out[2 * token]     = e1 * winv;
        out[2 * token + 1] = e2 * winv;
        out[2 * NTOK + 2 * token]     = (float)i1;   // indices as f32 (concat promotion)
        out[2 * NTOK + 2 * token + 1] = (float)i2;
        const float lse = m + __logf(ssum);
        atomicAdd(&sZ, lse * lse);
        atomicAdd(&sCnt[i1], 1.0f);
        atomicAdd(&sCnt[i2], 1.0f);
        sInv[g] = 1.0f / ssum;
    }
    __syncthreads();

    // ---- phase 2b: block-local P sums over 32 tokens, then global atomics
    {
        const int e = tid & 63;
        const int q = tid >> 6;
        float part = 0.0f;
        #pragma unroll
        for (int t = 0; t < 8; ++t) {
            const int tok = q * 8 + t;
            part += sLog[tok * SL + e] * sInv[tok];
        }
        sPp[q * 64 + e] = part;
    }
    __syncthreads();
    if (tid < 64) {
        const float ps = sPp[tid] + sPp[64 + tid] + sPp[128 + tid] + sPp[192 + tid];
        atomicAdd(&ws[tid], ps);             // sum of probs per expert
        atomicAdd(&ws[64 + tid], sCnt[tid]); // top-2 counts per expert
    }
    if (tid == 0) atomicAdd(&ws[128], sZ);
}

__global__ void finalize_kernel(const float* __restrict__ ws, float* __restrict__ out) {
    const int e = threadIdx.x;   // 64 threads, one wave
    const float P = ws[e] * (1.0f / NTOK);
    const float f = ws[64 + e] * (1.0f / (NTOK * 2));
    float term = f * P;
    #pragma unroll
    for (int s = 32; s >= 1; s >>= 1) term += __shfl_xor(term, s, 64);
    if (e == 0) {
        const float lb = 64.0f * term;
        const float z  = ws[128] * (1.0f / NTOK);
        out[4 * NTOK] = 0.001f * lb + 0.001f * z;
    }
}

extern "C" void kernel_launch(void* const* d_in, const int* in_sizes, int n_in,
                              void* d_out, int out_size, void* d_ws, size_t ws_size,
                              hipStream_t stream) {
    const float* hs = (const float*)d_in[0];
    const float* Wg = (const float*)d_in[1];
    float* out = (float*)d_out;
    float* ws  = (float*)d_ws;

    const size_t need = (size_t)WS_ACC_FLOATS * sizeof(float)
                      + (size_t)B_ELEMS * 2 * sizeof(__bf16);
    if (ws_size >= need) {
        const __bf16* Bhi = (const __bf16*)(ws + WS_ACC_FLOATS);
        const __bf16* Blo = Bhi + B_ELEMS;
        hipLaunchKernelGGL(prep_kernel, dim3(128), dim3(256), 0, stream, Wg, ws);
        hipLaunchKernelGGL((router_kernel<true>), dim3(NBLK), dim3(256), 0, stream,
                           hs, Wg, Bhi, Blo, out, ws);
    } else {
        hipLaunchKernelGGL(zero_ws_kernel, dim3(1), dim3(256), 0, stream, ws);
        hipLaunchKernelGGL((router_kernel<false>), dim3(NBLK), dim3(256), 0, stream,
                           hs, Wg, (const __bf16*)nullptr, (const __bf16*)nullptr, out, ws);
    }
    hipLaunchKernelGGL(finalize_kernel, dim3(1), dim3(64), 0, stream, ws, out);
}

// Round 2
// 437.102 us; speedup vs baseline: 1.0953x; 1.0953x over previous
//
#include <hip/hip_runtime.h>
#include <hip/hip_bf16.h>

#define NTOK 16384
#define HD   4096
#define NE   64
#define TTILE 32            // tokens per block
#define NBLK (NTOK / TTILE) // 512 blocks -> 2 blocks/CU
#define NIT  (HD / 32)      // 128 k-tiles

// LDS row strides (elements)
#define SAB 40   // bf16: 32 K-elems + 8 pad -> 80 B rows (80 = 5*16, keeps 16B align)
#define SL  68   // float stride for logits tile (32 x 64)

// ws layout (floats): [0,64)=P_sum, [64,128)=counts, [128]=z_sum, pad to 192,
// then Bhi (bf16, NE*HD elems), then Blo (bf16, NE*HD elems). Total ~1.05 MB.
#define WS_ACC_FLOATS 192
#define B_ELEMS (NE * HD)

typedef __bf16 bf16x8 __attribute__((ext_vector_type(8)));
typedef __bf16 bf16x4 __attribute__((ext_vector_type(4)));
typedef float  f32x4  __attribute__((ext_vector_type(4)));

__device__ __forceinline__ f32x4 mfma16(bf16x8 a, bf16x8 b, f32x4 c) {
    return __builtin_amdgcn_mfma_f32_16x16x32_bf16(a, b, c, 0, 0, 0);
}

__device__ __forceinline__ void cvt_split(float4 v, bf16x4& hi, bf16x4& lo) {
    float x[4] = {v.x, v.y, v.z, v.w};
    #pragma unroll
    for (int e = 0; e < 4; ++e) {
        __bf16 h = (__bf16)x[e];        // RNE
        hi[e] = h;
        lo[e] = (__bf16)(x[e] - (float)h);
    }
}

__global__ void zero_ws_kernel(float* ws) {
    int i = threadIdx.x;
    if (i < 129) ws[i] = 0.0f;
}

// One-shot: zero accumulators + convert W_gate fp32 -> bf16 hi/lo in ws.
// Grid 128 x 256 threads, 8 elems/thread = 64*4096 elems exactly.
__global__ __launch_bounds__(256) void prep_kernel(
    const float* __restrict__ Wg, float* __restrict__ ws)
{
    const int tid = threadIdx.x;
    if (blockIdx.x == 0 && tid < 129) ws[tid] = 0.0f;
    __bf16* Bhi = (__bf16*)(ws + WS_ACC_FLOATS);
    __bf16* Blo = Bhi + B_ELEMS;
    const int i = (blockIdx.x * 256 + tid) * 8;
    float4 v0 = *(const float4*)(Wg + i);
    float4 v1 = *(const float4*)(Wg + i + 4);
    bf16x4 h0, l0, h1, l1;
    cvt_split(v0, h0, l0);
    cvt_split(v1, h1, l1);
    *(bf16x4*)(Bhi + i)     = h0;
    *(bf16x4*)(Bhi + i + 4) = h1;
    *(bf16x4*)(Blo + i)     = l0;
    *(bf16x4*)(Blo + i + 4) = l1;
}

// Main router (PRE path): A double-buffered through LDS (proven schedule);
// B fragments loaded per-wave straight from pre-converted bf16 arrays,
// register-prefetched one full iteration ahead (issue->use distance covers
// L2 latency; barrier keeps waves clustered for L2 reuse).
__global__ __launch_bounds__(256) void router_pre_kernel(
    const float* __restrict__ hs,
    const __bf16* __restrict__ Bhi,
    const __bf16* __restrict__ Blo,
    float* __restrict__ out,
    float* __restrict__ ws)
{
    __shared__ __bf16 sAhi[2][TTILE * SAB];   // 5,120 B
    __shared__ __bf16 sAlo[2][TTILE * SAB];   // 5,120 B
    __shared__ float  sLog[TTILE * SL];       // 8,704 B
    __shared__ float  sInv[TTILE];
    __shared__ float  sPp[4 * 64];
    __shared__ float  sCnt[64];
    __shared__ float  sZ;

    const int tid = threadIdx.x;
    const int t0  = blockIdx.x * TTILE;

    if (tid < 64) sCnt[tid] = 0.0f;
    if (tid == 0) sZ = 0.0f;

    // ---- A staging: per iter each thread loads 1 float4 of A
    const int r1 = tid >> 3;            // 0..31
    const int c4 = (tid & 7) * 4;       // k offset (floats)
    const float* gA = hs + (size_t)(t0 + r1) * HD + c4;
    const int oA = r1 * SAB + c4;

    // ---- wave tile: 16 tok x 32 exp (1x2 MFMA tiles), 4 waves cover 32x64
    const int lane = tid & 63;
    const int wv   = tid >> 6;
    const int wr   = (wv >> 1) * 16;    // token offset: 0 or 16
    const int wc   = (wv & 1) * 32;     // expert offset: 0 or 32
    const int fm   = lane & 15;
    const int fq   = lane >> 4;         // 0..3
    const int fk   = fq * 8;            // k offset within 32-tile

    // B fragment global pointers: expert row = wc + j*16 + fm, k = it*32 + fk
    const __bf16* gBh = Bhi + (size_t)(wc + fm) * HD + fk;
    const __bf16* gBl = Blo + (size_t)(wc + fm) * HD + fk;

    f32x4 acc[2];
    acc[0] = (f32x4){0.f, 0.f, 0.f, 0.f};
    acc[1] = (f32x4){0.f, 0.f, 0.f, 0.f};

    // ---- prologue: stage A tile 0 -> buf 0; load B frags for tile 0
    {
        float4 a0 = *(const float4*)(gA);
        bf16x4 h, l;
        cvt_split(a0, h, l);
        *(bf16x4*)&sAhi[0][oA] = h;
        *(bf16x4*)&sAlo[0][oA] = l;
    }
    bf16x8 cbh[2], cbl[2];
    cbh[0] = *(const bf16x8*)(gBh);
    cbh[1] = *(const bf16x8*)(gBh + 16 * HD);
    cbl[0] = *(const bf16x8*)(gBl);
    cbl[1] = *(const bf16x8*)(gBl + 16 * HD);
    __syncthreads();

    #pragma unroll 2
    for (int it = 0; it < NIT; ++it) {
        const int cur = it & 1;
        const bool more = (it + 1) < NIT;

        // issue next-tile loads first (A f32 + B frags), consumed next iter
        float4 na;
        bf16x8 nbh0, nbh1, nbl0, nbl1;
        if (more) {
            const int k0 = (it + 1) * 32;
            na   = *(const float4*)(gA + k0);
            nbh0 = *(const bf16x8*)(gBh + k0);
            nbh1 = *(const bf16x8*)(gBh + 16 * HD + k0);
            nbl0 = *(const bf16x8*)(gBl + k0);
            nbl1 = *(const bf16x8*)(gBl + 16 * HD + k0);
        }

        // ---- compute on current buffer: 2 ds_read_b128, 8 MFMAs
        bf16x8 ahi, alo;
        {
            const int aoff = (wr + fm) * SAB + fk;
            ahi = *(const bf16x8*)&sAhi[cur][aoff];
            alo = *(const bf16x8*)&sAlo[cur][aoff];
        }
        // 4-term exact split, same accumulation order as the passing kernel
        acc[0] = mfma16(ahi, cbh[0], acc[0]);
        acc[0] = mfma16(ahi, cbl[0], acc[0]);
        acc[0] = mfma16(alo, cbh[0], acc[0]);
        acc[0] = mfma16(alo, cbl[0], acc[0]);
        acc[1] = mfma16(ahi, cbh[1], acc[1]);
        acc[1] = mfma16(ahi, cbl[1], acc[1]);
        acc[1] = mfma16(alo, cbh[1], acc[1]);
        acc[1] = mfma16(alo, cbl[1], acc[1]);

        if (more) {
            bf16x4 h, l;
            cvt_split(na, h, l);
            *(bf16x4*)&sAhi[cur ^ 1][oA] = h;
            *(bf16x4*)&sAlo[cur ^ 1][oA] = l;
            cbh[0] = nbh0; cbh[1] = nbh1;
            cbl[0] = nbl0; cbl[1] = nbl1;
        }
        __syncthreads();
    }

    // ---- scatter logits to LDS: C/D layout col=lane&15 (expert), row=fq*4+reg
    #pragma unroll
    for (int j = 0; j < 2; ++j)
        #pragma unroll
        for (int r = 0; r < 4; ++r) {
            const int tokl = wr + fq * 4 + r;
            const int expl = wc + j * 16 + fm;
            sLog[tokl * SL + expl] = acc[j][r];
        }
    __syncthreads();

    // ---- phase 2a: softmax/top-2; 8 lanes per token, 8 experts per lane
    const int g = tid >> 3;       // token 0..31
    const int l = tid & 7;
    float* Lrow = &sLog[g * SL + l * 8];
    float lv[8];
    float m = -3.0e38f;
    #pragma unroll
    for (int c = 0; c < 8; ++c) { lv[c] = Lrow[c]; m = fmaxf(m, lv[c]); }
    m = fmaxf(m, __shfl_xor(m, 1, 64));
    m = fmaxf(m, __shfl_xor(m, 2, 64));
    m = fmaxf(m, __shfl_xor(m, 4, 64));

    float v1 = -3.0e38f, v2 = -3.0e38f; int i1 = 0, i2 = 0;
    float ssum = 0.0f;
    #pragma unroll
    for (int c = 0; c < 8; ++c) {
        const float val = lv[c]; const int idx = l * 8 + c;
        const float ev = __expf(val - m);
        Lrow[c] = ev;               // overwrite logits with exp(l - m)
        ssum += ev;
        if (val > v1) { v2 = v1; i2 = i1; v1 = val; i1 = idx; }
        else if (val > v2) { v2 = val; i2 = idx; }
    }
    ssum += __shfl_xor(ssum, 1, 64);
    ssum += __shfl_xor(ssum, 2, 64);
    ssum += __shfl_xor(ssum, 4, 64);

    #pragma unroll
    for (int s = 1; s <= 4; s <<= 1) {
        const float ov1 = __shfl_xor(v1, s, 64);
        const int   oi1 = __shfl_xor(i1, s, 64);
        const float ov2 = __shfl_xor(v2, s, 64);
        const int   oi2 = __shfl_xor(i2, s, 64);
        float n1, n2; int ni1, ni2;
        const bool ofirst = (ov1 > v1) || (ov1 == v1 && oi1 < i1);
        if (ofirst) {
            n1 = ov1; ni1 = oi1;
            const bool osec = (ov2 > v1) || (ov2 == v1 && oi2 < i1);
            n2 = osec ? ov2 : v1; ni2 = osec ? oi2 : i1;
        } else {
            n1 = v1; ni1 = i1;
            const bool asec = (v2 > ov1) || (v2 == ov1 && i2 < oi1);
            n2 = asec ? v2 : ov1; ni2 = asec ? i2 : oi1;
        }
        v1 = n1; i1 = ni1; v2 = n2; i2 = ni2;
    }

    if (l == 0) {
        const float e1 = __expf(v1 - m), e2 = __expf(v2 - m);
        const float winv = 1.0f / (e1 + e2);
        const int token = t0 + g;
        out[2 * token]     = e1 * winv;
        out[2 * token + 1] = e2 * winv;
        out[2 * NTOK + 2 * token]     = (float)i1;   // indices as f32 (concat promotion)
        out[2 * NTOK + 2 * token + 1] = (float)i2;
        const float lse = m + __logf(ssum);
        atomicAdd(&sZ, lse * lse);
        atomicAdd(&sCnt[i1], 1.0f);
        atomicAdd(&sCnt[i2], 1.0f);
        sInv[g] = 1.0f / ssum;
    }
    __syncthreads();

    // ---- phase 2b: block-local P sums over 32 tokens, then global atomics
    {
        const int e = tid & 63;
        const int q = tid >> 6;
        float part = 0.0f;
        #pragma unroll
        for (int t = 0; t < 8; ++t) {
            const int tok = q * 8 + t;
            part += sLog[tok * SL + e] * sInv[tok];
        }
        sPp[q * 64 + e] = part;
    }
    __syncthreads();
    if (tid < 64) {
        const float ps = sPp[tid] + sPp[64 + tid] + sPp[128 + tid] + sPp[192 + tid];
        atomicAdd(&ws[tid], ps);             // sum of probs per expert
        atomicAdd(&ws[64 + tid], sCnt[tid]); // top-2 counts per expert
    }
    if (tid == 0) atomicAdd(&ws[128], sZ);
}

// Fallback (ws too small for B copies): the round-0 verified kernel,
// in-loop fp32->bf16 split for both A and B, full LDS staging.
__global__ __launch_bounds__(256) void router_fb_kernel(
    const float* __restrict__ hs,
    const float* __restrict__ Wg,
    float* __restrict__ out,
    float* __restrict__ ws)
{
    __shared__ __bf16 sAhi[2][TTILE * SAB];
    __shared__ __bf16 sAlo[2][TTILE * SAB];
    __shared__ __bf16 sBhi[2][NE * SAB];
    __shared__ __bf16 sBlo[2][NE * SAB];
    __shared__ float  sLog[TTILE * SL];
    __shared__ float  sInv[TTILE];
    __shared__ float  sPp[4 * 64];
    __shared__ float  sCnt[64];
    __shared__ float  sZ;

    const int tid = threadIdx.x;
    const int t0  = blockIdx.x * TTILE;

    if (tid < 64) sCnt[tid] = 0.0f;
    if (tid == 0) sZ = 0.0f;

    const int r1 = tid >> 3;
    const int c4 = (tid & 7) * 4;
    const float* gA = hs + (size_t)(t0 + r1) * HD + c4;
    const float* gB = Wg + (size_t)r1 * HD + c4;
    const int oA  = r1 * SAB + c4;
    const int oB1 = r1 * SAB + c4;
    const int oB2 = (r1 + 32) * SAB + c4;

    const int lane = tid & 63;
    const int wv   = tid >> 6;
    const int wr   = (wv >> 1) * 16;
    const int wc   = (wv & 1) * 32;
    const int fm   = lane & 15;
    const int fq   = lane >> 4;
    const int fk   = fq * 8;

    f32x4 acc[2];
    acc[0] = (f32x4){0.f, 0.f, 0.f, 0.f};
    acc[1] = (f32x4){0.f, 0.f, 0.f, 0.f};

    {
        float4 a0 = *(const float4*)(gA);
        float4 b0 = *(const float4*)(gB);
        float4 b1 = *(const float4*)(gB + 32 * HD);
        bf16x4 h, l;
        cvt_split(a0, h, l); *(bf16x4*)&sAhi[0][oA]  = h; *(bf16x4*)&sAlo[0][oA]  = l;
        cvt_split(b0, h, l); *(bf16x4*)&sBhi[0][oB1] = h; *(bf16x4*)&sBlo[0][oB1] = l;
        cvt_split(b1, h, l); *(bf16x4*)&sBhi[0][oB2] = h; *(bf16x4*)&sBlo[0][oB2] = l;
    }
    __syncthreads();

    for (int it = 0; it < NIT; ++it) {
        const int cur = it & 1;
        const bool more = (it + 1) < NIT;
        float4 na0, nb0, nb1;
        if (more) {
            const int k0 = (it + 1) * 32;
            na0 = *(const float4*)(gA + k0);
            nb0 = *(const float4*)(gB + k0);
            nb1 = *(const float4*)(gB + 32 * HD + k0);
        }

        bf16x8 ahi, alo, bhi[2], blo[2];
        {
            const int aoff = (wr + fm) * SAB + fk;
            ahi = *(const bf16x8*)&sAhi[cur][aoff];
            alo = *(const bf16x8*)&sAlo[cur][aoff];
        }
        #pragma unroll
        for (int j = 0; j < 2; ++j) {
            const int boff = (wc + j * 16 + fm) * SAB + fk;
            bhi[j] = *(const bf16x8*)&sBhi[cur][boff];
            blo[j] = *(const bf16x8*)&sBlo[cur][boff];
        }
        #pragma unroll
        for (int j = 0; j < 2; ++j) {
            acc[j] = mfma16(ahi, bhi[j], acc[j]);
            acc[j] = mfma16(ahi, blo[j], acc[j]);
            acc[j] = mfma16(alo, bhi[j], acc[j]);
            acc[j] = mfma16(alo, blo[j], acc[j]);
        }

        if (more) {
            const int nb = cur ^ 1;
            bf16x4 h, l;
            cvt_split(na0, h, l); *(bf16x4*)&sAhi[nb][oA]  = h; *(bf16x4*)&sAlo[nb][oA]  = l;
            cvt_split(nb0, h, l); *(bf16x4*)&sBhi[nb][oB1] = h; *(bf16x4*)&sBlo[nb][oB1] = l;
            cvt_split(nb1, h, l); *(bf16x4*)&sBhi[nb][oB2] = h; *(bf16x4*)&sBlo[nb][oB2] = l;
        }
        __syncthreads();
    }

    #pragma unroll
    for (int j = 0; j < 2; ++j)
        #pragma unroll
        for (int r = 0; r < 4; ++r) {
            const int tokl = wr + fq * 4 + r;
            const int expl = wc + j * 16 + fm;
            sLog[tokl * SL + expl] = acc[j][r];
        }
    __syncthreads();

    const int g = tid >> 3;
    const int l = tid & 7;
    float* Lrow = &sLog[g * SL + l * 8];
    float lv[8];
    float m = -3.0e38f;
    #pragma unroll
    for (int c = 0; c < 8; ++c) { lv[c] = Lrow[c]; m = fmaxf(m, lv[c]); }
    m = fmaxf(m, __shfl_xor(m, 1, 64));
    m = fmaxf(m, __shfl_xor(m, 2, 64));
    m = fmaxf(m, __shfl_xor(m, 4, 64));

    float v1 = -3.0e38f, v2 = -3.0e38f; int i1 = 0, i2 = 0;
    float ssum = 0.0f;
    #pragma unroll
    for (int c = 0; c < 8; ++c) {
        const float val = lv[c]; const int idx = l * 8 + c;
        const float ev = __expf(val - m);
        Lrow[c] = ev;
        ssum += ev;
        if (val > v1) { v2 = v1; i2 = i1; v1 = val; i1 = idx; }
        else if (val > v2) { v2 = val; i2 = idx; }
    }
    ssum += __shfl_xor(ssum, 1, 64);
    ssum += __shfl_xor(ssum, 2, 64);
    ssum += __shfl_xor(ssum, 4, 64);

    #pragma unroll
    for (int s = 1; s <= 4; s <<= 1) {
        const float ov1 = __shfl_xor(v1, s, 64);
        const int   oi1 = __shfl_xor(i1, s, 64);
        const float ov2 = __shfl_xor(v2, s, 64);
        const int   oi2 = __shfl_xor(i2, s, 64);
        float n1, n2; int ni1, ni2;
        const bool ofirst = (ov1 > v1) || (ov1 == v1 && oi1 < i1);
        if (ofirst) {
            n1 = ov1; ni1 = oi1;
            const bool osec = (ov2 > v1) || (ov2 == v1 && oi2 < i1);
            n2 = osec ? ov2 : v1; ni2 = osec ? oi2 : i1;
        } else {
            n1 = v1; ni1 = i1;
            const bool asec = (v2 > ov1) || (v2 == ov1 && i2 < oi1);
            n2 = asec ? v2 : ov1; ni2 = asec ? i2 : oi1;
        }
        v1 = n1; i1 = ni1; v2 = n2; i2 = ni2;
    }

    if (l == 0) {
        const float e1 = __expf(v1 - m), e2 = __expf(v2 - m);
        const float winv = 1.0f / (e1 + e2);
        const int token = t0 + g;
        out[2 * token]     = e1 * winv;
        out[2 * token + 1] = e2 * winv;
        out[2 * NTOK + 2 * token]     = (float)i1;
        out[2 * NTOK + 2 * token + 1] = (float)i2;
        const float lse = m + __logf(ssum);
        atomicAdd(&sZ, lse * lse);
        atomicAdd(&sCnt[i1], 1.0f);
        atomicAdd(&sCnt[i2], 1.0f);
        sInv[g] = 1.0f / ssum;
    }
    __syncthreads();

    {
        const int e = tid & 63;
        const int q = tid >> 6;
        float part = 0.0f;
        #pragma unroll
        for (int t = 0; t < 8; ++t) {
            const int tok = q * 8 + t;
            part += sLog[tok * SL + e] * sInv[tok];
        }
        sPp[q * 64 + e] = part;
    }
    __syncthreads();
    if (tid < 64) {
        const float ps = sPp[tid] + sPp[64 + tid] + sPp[128 + tid] + sPp[192 + tid];
        atomicAdd(&ws[tid], ps);
        atomicAdd(&ws[64 + tid], sCnt[tid]);
    }
    if (tid == 0) atomicAdd(&ws[128], sZ);
}

__global__ void finalize_kernel(const float* __restrict__ ws, float* __restrict__ out) {
    const int e = threadIdx.x;   // 64 threads, one wave
    const float P = ws[e] * (1.0f / NTOK);
    const float f = ws[64 + e] * (1.0f / (NTOK * 2));
    float term = f * P;
    #pragma unroll
    for (int s = 32; s >= 1; s >>= 1) term += __shfl_xor(term, s, 64);
    if (e == 0) {
        const float lb = 64.0f * term;
        const float z  = ws[128] * (1.0f / NTOK);
        out[4 * NTOK] = 0.001f * lb + 0.001f * z;
    }
}

extern "C" void kernel_launch(void* const* d_in, const int* in_sizes, int n_in,
                              void* d_out, int out_size, void* d_ws, size_t ws_size,
                              hipStream_t stream) {
    const float* hs = (const float*)d_in[0];
    const float* Wg = (const float*)d_in[1];
    float* out = (float*)d_out;
    float* ws  = (float*)d_ws;

    const size_t need = (size_t)WS_ACC_FLOATS * sizeof(float)
                      + (size_t)B_ELEMS * 2 * sizeof(__bf16);
    if (ws_size >= need) {
        const __bf16* Bhi = (const __bf16*)(ws + WS_ACC_FLOATS);
        const __bf16* Blo = Bhi + B_ELEMS;
        hipLaunchKernelGGL(prep_kernel, dim3(128), dim3(256), 0, stream, Wg, ws);
        hipLaunchKernelGGL(router_pre_kernel, dim3(NBLK), dim3(256), 0, stream,
                           hs, Bhi, Blo, out, ws);
    } else {
        hipLaunchKernelGGL(zero_ws_kernel, dim3(1), dim3(256), 0, stream, ws);
        hipLaunchKernelGGL(router_fb_kernel, dim3(NBLK), dim3(256), 0, stream,
                           hs, Wg, out, ws);
    }
    hipLaunchKernelGGL(finalize_kernel, dim3(1), dim3(64), 0, stream, ws, out);
}